// Round 17
// baseline (438.083 us; speedup 1.0000x reference)
//
#include <hip/hip_runtime.h>

#define BDIM 512
#define PACK_BDIM 256

typedef __attribute__((ext_vector_type(8))) short bf16x8;
typedef __attribute__((ext_vector_type(4))) float f32x4;
typedef __attribute__((ext_vector_type(16))) float f32x16;
typedef __attribute__((ext_vector_type(4))) unsigned int u32x4;

__device__ __forceinline__ unsigned short f2b(float x) {   // round-to-nearest-even
    unsigned u = __float_as_uint(x);
    return (unsigned short)((u + 0x7fffu + ((u >> 16) & 1u)) >> 16);
}

typedef __attribute__((address_space(1))) const unsigned int ga_u32;
typedef __attribute__((address_space(3))) unsigned int la_u32;
__device__ __forceinline__ void gload_lds16(const void* g, void* l) {
    __builtin_amdgcn_global_load_lds((ga_u32*)g, (la_u32*)l, 16, 0, 0);
}

// Pack 9 fp32 128x128 weights to RTN bf16 in 32x32x16 B-fragment order:
// per gemm g (32768 B at wp + g*16384 shorts): chunk q = s*4+F (s=kstep 0..7,
// F=colfrag 0..3; 1 KB each), byte = lane*16 holding 8 bf16 for
// k = s*16 + (lane>>5)*8 + i, n = F*32 + (lane&31), packed lo=even-k.
// Bias fp32 at short-offset 147456 (byte 294912): biasf[g*128 + col].
__global__ __launch_bounds__(PACK_BDIM) void pack_weights(
    const float* __restrict__ w0, const float* __restrict__ w1,
    const float* __restrict__ w2, const float* __restrict__ w3,
    const float* __restrict__ w4, const float* __restrict__ w5,
    const float* __restrict__ w6, const float* __restrict__ w7,
    const float* __restrict__ w8,
    const float* __restrict__ b0, const float* __restrict__ b1,
    const float* __restrict__ b2, const float* __restrict__ b3,
    const float* __restrict__ b4, const float* __restrict__ b5,
    const float* __restrict__ b6, const float* __restrict__ b7,
    const float* __restrict__ b8, unsigned short* __restrict__ wp)
{
    __shared__ float wsm[16384];
    const float* W; const float* Bp;
    switch (blockIdx.x) {
        case 0: W = w0; Bp = b0; break; case 1: W = w1; Bp = b1; break;
        case 2: W = w2; Bp = b2; break; case 3: W = w3; Bp = b3; break;
        case 4: W = w4; Bp = b4; break; case 5: W = w5; Bp = b5; break;
        case 6: W = w6; Bp = b6; break; case 7: W = w7; Bp = b7; break;
        default: W = w8; Bp = b8; break;
    }
    const int tid = threadIdx.x;
    for (int i = tid; i < 16384; i += PACK_BDIM) wsm[i] = W[i];
    float* biasf = (float*)(wp + 147456);
    if (tid < 128) biasf[blockIdx.x * 128 + tid] = Bp[tid];
    __syncthreads();
    unsigned short* dst = wp + (size_t)blockIdx.x * 16384;
    for (int item = tid; item < 2048; item += PACK_BDIM) {
        const int lane = item & 63, q = item >> 6;   // q = s*4 + F
        const int s = q >> 2, F = q & 3;
        const int k0 = s * 16 + (lane >> 5) * 8;
        const int n  = F * 32 + (lane & 31);
        u32x4 vv;
        for (int i2 = 0; i2 < 4; i2++) {
            unsigned short lo = f2b(wsm[(k0 + 2 * i2)     * 128 + n]);
            unsigned short hi = f2b(wsm[(k0 + 2 * i2 + 1) * 128 + n]);
            vv[i2] = (unsigned)lo | ((unsigned)hi << 16);
        }
        *(u32x4*)(dst + (size_t)q * 512 + lane * 8) = vv;
    }
}

// Fused dual-input GRU cell. grid = B/64, 512 thr = 8 waves = 2 rowgrp x
// 4 colgrp; per wave 32 rows x 32 cols via ONE mfma_f32_32x32x16_bf16 frag
// per accumulator set (16 regs). vs R16 (16x16 shape): LDS B-reads per
// phase HALVED (B-bytes/output = K*2/rows_per_tile), MFMA inst count
// halved at the faster 32x32 shape, bias = 1 scalar/lane. Schedule, 2-term
// split (W RTN bf16, A = ah+al trunc split), buffers = R16 exactly.
// A-frag: row=lane&31, k=(lane>>5)*8+i. C/D: col=lane&31,
// row=(reg&3)+8*(reg>>2)+4*(lane>>5) [m74/m101].
// order u: 0 hr(6), 1 ir(0), 2 sr(3), 3 hn(8,LDS-A), 4 in(2), 5 sn(5),
//          6 hz(7), 7 iz(1), 8 sz(4).
__global__ __launch_bounds__(BDIM) __attribute__((amdgpu_waves_per_eu(4)))
void gru_fused(
    const float* __restrict__ inp, const float* __restrict__ seqp,
    const float* __restrict__ hid, const unsigned short* __restrict__ wp,
    float* __restrict__ outp)
{
    __shared__ __align__(16) unsigned short wbuf[2][16384]; // 2 x 32 KiB
    float* tbR = (float*)wbuf[1];   // rh transpose overlay (u2 -> u3)
    float* tbO = (float*)wbuf[0];   // output transpose overlay (epilogue)

    const int tid    = threadIdx.x;
    const int lane   = tid & 63;
    const int wid    = tid >> 6;       // 0..7
    const int rowgrp = wid >> 2;       // 0..1
    const int colgrp = wid & 3;        // 0..3
    const int l31    = lane & 31;
    const int kgrp   = lane >> 5;      // 0..1
    const size_t row0 = (size_t)blockIdx.x * 64;
    const int locrow_a = rowgrp * 32 + l31;    // A-layout row 0..63
    const int rswA = (locrow_a & 7) << 3;
    const int ocol = colgrp * 32 + l31;        // output col 0..127

    const float* pAin  = inp  + (row0 + locrow_a) * 128;
    const float* pAseq = seqp + (row0 + locrow_a) * 128;
    const float* pAhid = hid  + (row0 + locrow_a) * 128;
    const float* biasf = (const float*)(wp + 147456);

    f32x16 hx, s1, nacc, G;
    const f32x16 zv = {0.f,0.f,0.f,0.f,0.f,0.f,0.f,0.f,
                       0.f,0.f,0.f,0.f,0.f,0.f,0.f,0.f};

    auto stageu = [&](int g, int b) {   // issue 32KB stage, no wait
        const char* src = (const char*)wp + (size_t)g * 32768;
        char* dstb = (char*)wbuf[b];
        #pragma unroll
        for (int j = 0; j < 4; j++) {
            const int off = (j * 8 + wid) * 1024;  // wave-uniform LDS base
            gload_lds16(src + off + lane * 16, dstb + off);
        }
    };

    // Trunc split A -> ah (bf16 hi) + al (remainder as bf16); ah+al ~= A
    // to ~2^-17 rel. perm(e1,e0,0x07060302) packs two bf16-hi in one inst.
    auto splitc2 = [&](f32x4 x0, f32x4 x1, bf16x8& ah, bf16x8& al) {
        u32x4 a, l;
        #pragma unroll
        for (int p = 0; p < 2; p++) {
            unsigned e0 = __float_as_uint(x0[2 * p]);
            unsigned e1 = __float_as_uint(x0[2 * p + 1]);
            a[p] = __builtin_amdgcn_perm(e1, e0, 0x07060302u);
            float d0 = x0[2 * p]     - __uint_as_float(e0 & 0xffff0000u);
            float d1 = x0[2 * p + 1] - __uint_as_float(e1 & 0xffff0000u);
            l[p] = __builtin_amdgcn_perm(__float_as_uint(d1), __float_as_uint(d0), 0x07060302u);
            unsigned f0 = __float_as_uint(x1[2 * p]);
            unsigned f1 = __float_as_uint(x1[2 * p + 1]);
            a[2 + p] = __builtin_amdgcn_perm(f1, f0, 0x07060302u);
            float g0 = x1[2 * p]     - __uint_as_float(f0 & 0xffff0000u);
            float g1 = x1[2 * p + 1] - __uint_as_float(f1 & 0xffff0000u);
            l[2 + p] = __builtin_amdgcn_perm(__float_as_uint(g1), __float_as_uint(g0), 0x07060302u);
        }
        ah = *(const bf16x8*)&a;
        al = *(const bf16x8*)&l;
    };

    // G = (Ah+Al) @ W + bias  (A from global, W RTN bf16 from wbuf[b])
    auto gemmG = [&](int b, const float* pA, int g) {
        G = zv;
        const unsigned short* wb = wbuf[b];
        #pragma unroll
        for (int s = 0; s < 8; s++) {
            const float* p = pA + s * 16 + kgrp * 8;
            bf16x8 ah, al;
            splitc2(*(const f32x4*)p, *(const f32x4*)(p + 4), ah, al);
            const bf16x8 w = *(const bf16x8*)(&wb[(size_t)(s * 4 + colgrp) * 512 + lane * 8]);
            G = __builtin_amdgcn_mfma_f32_32x32x16_bf16(ah, w, G, 0, 0, 0);
            G = __builtin_amdgcn_mfma_f32_32x32x16_bf16(al, w, G, 0, 0, 0);
        }
        const float bv = biasf[g * 128 + ocol];
        #pragma unroll
        for (int r = 0; r < 16; r++) G[r] += bv;
    };

    // hn: A rows = rh from tbR (buf1, XOR-swizzled), W from buf0
    auto gemmL = [&](int g) {
        G = zv;
        const unsigned short* wb = wbuf[0];
        #pragma unroll
        for (int s = 0; s < 8; s++) {
            const int rk = (s * 16 + kgrp * 8) ^ rswA;
            f32x4 x0 = *(const f32x4*)(&tbR[locrow_a * 128 + rk]);
            f32x4 x1 = *(const f32x4*)(&tbR[locrow_a * 128 + rk + 4]);
            bf16x8 ah, al;
            splitc2(x0, x1, ah, al);
            const bf16x8 w = *(const bf16x8*)(&wb[(size_t)(s * 4 + colgrp) * 512 + lane * 8]);
            G = __builtin_amdgcn_mfma_f32_32x32x16_bf16(ah, w, G, 0, 0, 0);
            G = __builtin_amdgcn_mfma_f32_32x32x16_bf16(al, w, G, 0, 0, 0);
        }
        const float bv = biasf[g * 128 + ocol];
        #pragma unroll
        for (int r = 0; r < 16; r++) G[r] += bv;
    };

    auto sigm = [](float x) { return 1.f / (1.f + __expf(-x)); };
    auto tanh_ = [](float x) {
        x = fminf(18.f, fmaxf(-18.f, x));
        float e = __expf(2.f * x);
        return (e - 1.f) / (e + 1.f);
    };

    const unsigned long long GT = 0x417528306ULL;  // nibble u -> gemm id
    const unsigned CBT = 0x152u;                   // bit u -> compute buffer
    stageu(6, 0);                                  // prologue: W_hr -> buf0

    #pragma clang loop unroll(disable)
    for (int u = 0; u < 9; ++u) {
        const int g = (int)((GT >> (4 * u)) & 15);
        __syncthreads();               // drains W(g) stage; prior readers done
        if (u == 3) {
            gemmL(g);                  // A = rh (buf1), W = buf0
        } else {
            if (u != 2 && u != 8)      // prefetch next gemm's W
                stageu((int)((GT >> (4 * (u + 1))) & 15), (CBT >> (u + 1)) & 1);
            const float* pA = (u == 0 || u == 6) ? pAhid
                            : (u == 1 || u == 4 || u == 7) ? pAin : pAseq;
            gemmG((CBT >> u) & 1, pA, g);
        }
        // ---- merge G into persistent state ----
        switch (u) {
            case 0: case 6:
                hx = G;
                break;
            case 1: case 7:
                #pragma unroll
                for (int r = 0; r < 16; r++) s1[r] = sigm(G[r] + hx[r]);
                break;
            case 2: {                  // r = 0.5(s1 + sigm(G+hx)); rh -> buf1
                #pragma unroll
                for (int r = 0; r < 16; r++) {
                    int row = rowgrp * 32 + (r & 3) + 8 * (r >> 2) + 4 * kgrp;
                    float rr = 0.5f * (s1[r] + sigm(G[r] + hx[r]));
                    float h = hid[(row0 + row) * 128 + ocol];
                    tbR[row * 128 + (ocol ^ ((row & 7) << 3))] = rr * h;
                }
                break;
            }
            case 3:
                nacc = G;
                break;
            case 4: case 5:
                #pragma unroll
                for (int r = 0; r < 16; r++) nacc[r] += G[r];
                break;
            default:                   // u == 8: G holds sz result
                break;
        }
        if (u == 2) { __syncthreads(); stageu(8, 0); }  // rh published; W_hn
        if (u == 3) { __syncthreads(); stageu(2, 1); }  // rh readers done; W_in
    }

    // ---- blend: z = 0.5(s1 + sigm(G+hx)); out = (1-z)tanh(nacc) + z*h ----
    // buf0's last readers were u7; all waves passed u8's top barrier -> free.
    #pragma unroll
    for (int r = 0; r < 16; r++) {
        int row = rowgrp * 32 + (r & 3) + 8 * (r >> 2) + 4 * kgrp;
        float zz = 0.5f * (s1[r] + sigm(G[r] + hx[r]));
        float h  = hid[(row0 + row) * 128 + ocol];
        float nn = tanh_(nacc[r]);
        tbO[row * 128 + (ocol ^ ((row & 7) << 3))] = (1.f - zz) * nn + zz * h;
    }
    __syncthreads();
    #pragma unroll
    for (int p = 0; p < 4; p++) {
        int e = p * 2048 + tid * 4;
        int rrow = e >> 7, c0 = e & 127;
        f32x4 v = *(const f32x4*)(&tbO[rrow * 128 + (c0 ^ ((rrow & 7) << 3))]);
        *(f32x4*)(&outp[(row0 + rrow) * 128 + c0]) = v;
    }
}

extern "C" void kernel_launch(void* const* d_in, const int* in_sizes, int n_in,
                              void* d_out, int out_size, void* d_ws, size_t ws_size,
                              hipStream_t stream)
{
    (void)in_sizes; (void)n_in; (void)out_size; (void)ws_size;
    const float* inp  = (const float*)d_in[0];
    const float* seqp = (const float*)d_in[1];
    const float* hid  = (const float*)d_in[2];
    const float* W[9]; const float* Bv[9];
    for (int i = 0; i < 9; i++) {
        W[i]  = (const float*)d_in[3 + 2 * i];
        Bv[i] = (const float*)d_in[4 + 2 * i];
    }
    unsigned short* wp = (unsigned short*)d_ws; // needs 294,912 + 4,608 B

    pack_weights<<<9, PACK_BDIM, 0, stream>>>(W[0], W[1], W[2], W[3], W[4],
                                              W[5], W[6], W[7], W[8],
                                              Bv[0], Bv[1], Bv[2], Bv[3], Bv[4],
                                              Bv[5], Bv[6], Bv[7], Bv[8], wp);
    gru_fused<<<2048, BDIM, 0, stream>>>(inp, seqp, hid, wp, (float*)d_out);
}

// Round 19
// 434.835 us; speedup vs baseline: 1.0075x; 1.0075x over previous
//
#include <hip/hip_runtime.h>

#define BDIM 1024
#define PACK_BDIM 256

typedef __attribute__((ext_vector_type(8))) short bf16x8;
typedef __attribute__((ext_vector_type(4))) float f32x4;
typedef __attribute__((ext_vector_type(4))) unsigned int u32x4;
typedef __attribute__((ext_vector_type(2))) __fp16 f16x2;

__device__ __forceinline__ unsigned short f2b(float x) {   // round-to-nearest-even
    unsigned u = __float_as_uint(x);
    return (unsigned short)((u + 0x7fffu + ((u >> 16) & 1u)) >> 16);
}

typedef __attribute__((address_space(1))) const unsigned int ga_u32;
typedef __attribute__((address_space(3))) unsigned int la_u32;
__device__ __forceinline__ void gload_lds16(const void* g, void* l) {
    __builtin_amdgcn_global_load_lds((ga_u32*)g, (la_u32*)l, 16, 0, 0);
}

// Pack 9 fp32 128x128 weights into RTN bf16 (32 KB per gemm, 16x16 frag
// layout: chunk cf=c*8+f (1 KB), byte=lane*16: 8 bf16 for
// k=c*32+(lane>>4)*8+i, n=f*16+(lane&15)), plus 9 fp32 biases at
// short-offset 147456: biasf[g*128 + col].
__global__ __launch_bounds__(PACK_BDIM) void pack_weights(
    const float* __restrict__ w0, const float* __restrict__ w1,
    const float* __restrict__ w2, const float* __restrict__ w3,
    const float* __restrict__ w4, const float* __restrict__ w5,
    const float* __restrict__ w6, const float* __restrict__ w7,
    const float* __restrict__ w8,
    const float* __restrict__ b0, const float* __restrict__ b1,
    const float* __restrict__ b2, const float* __restrict__ b3,
    const float* __restrict__ b4, const float* __restrict__ b5,
    const float* __restrict__ b6, const float* __restrict__ b7,
    const float* __restrict__ b8, unsigned short* __restrict__ wp)
{
    __shared__ float wsm[16384];
    const float* W; const float* Bp;
    switch (blockIdx.x) {
        case 0: W = w0; Bp = b0; break; case 1: W = w1; Bp = b1; break;
        case 2: W = w2; Bp = b2; break; case 3: W = w3; Bp = b3; break;
        case 4: W = w4; Bp = b4; break; case 5: W = w5; Bp = b5; break;
        case 6: W = w6; Bp = b6; break; case 7: W = w7; Bp = b7; break;
        default: W = w8; Bp = b8; break;
    }
    const int tid = threadIdx.x;
    for (int i = tid; i < 16384; i += PACK_BDIM) wsm[i] = W[i];
    float* biasf = (float*)(wp + 147456);
    if (tid < 128) biasf[blockIdx.x * 128 + tid] = Bp[tid];
    __syncthreads();
    unsigned short* dst = wp + (size_t)blockIdx.x * 16384;
    for (int item = tid; item < 2048; item += PACK_BDIM) {
        const int lane = item & 63, cf = item >> 6;    // cf = c*8+f
        const int c = cf >> 3, f = cf & 7;
        const int k0 = c * 32 + (lane >> 4) * 8;
        const int n  = f * 16 + (lane & 15);
        u32x4 vv;
        for (int i2 = 0; i2 < 4; i2++) {
            unsigned short lo = f2b(wsm[(k0 + 2 * i2)     * 128 + n]);
            unsigned short hi = f2b(wsm[(k0 + 2 * i2 + 1) * 128 + n]);
            vv[i2] = (unsigned)lo | ((unsigned)hi << 16);
        }
        *(u32x4*)(dst + (size_t)cf * 512 + lane * 8) = vv;
    }
}

// Fused dual-input GRU cell, wave-owned-rows structure.
// grid = B/256 = 512 blocks, 1024 thr = 16 waves; each wave owns 16 rows
// END-TO-END (full 128 cols). Weights staged in 3 groups of 3 gemms
// (96 KB RTN-bf16): g1{hr,ir,sr} -> g2{hn,in,sn} -> g3{hz,iz,sz}. Within
// a group waves FREE-RUN (zero barriers, no inter-wave deps). 6 barriers
// per 256 rows vs R13's ~176 (the diagnosed 50% stall source). r->hn
// transpose is wave-local: rh (packed hi|lo bf16 u32) bounces through a
// per-wave 8 KB slice carved from the dead g1 wbuf + tscr (swizzled).
// n survives g2->g3 as f16-packed registers (err 2^-11). 2-term split
// numerics = R16 (absmax-bit-identical class).
__global__ __launch_bounds__(BDIM) __attribute__((amdgpu_waves_per_eu(4)))
void gru_fused(
    const float* __restrict__ inp, const float* __restrict__ seqp,
    const float* __restrict__ hid, const unsigned short* __restrict__ wp,
    float* __restrict__ outp)
{
    __shared__ __align__(16) unsigned short wbuf[3][16384]; // 96 KiB
    __shared__ __align__(16) float tscr[8192];              // 32 KiB

    const int tid  = threadIdx.x;
    const int lane = tid & 63;
    const int wid  = tid >> 6;         // 0..15
    const int a16  = lane & 15;
    const int agrp = lane >> 4;
    const size_t row0 = (size_t)blockIdx.x * 256 + wid * 16;  // wave's rows

    const float* pAin  = inp  + (row0 + a16) * 128;
    const float* pAseq = seqp + (row0 + a16) * 128;
    const float* pAhid = hid  + (row0 + a16) * 128;
    const float* biasf = (const float*)(wp + 147456);

    auto stage3 = [&](int ga, int gb, int gc) {
        const int gs[3] = {ga, gb, gc};
        #pragma unroll
        for (int s = 0; s < 3; s++) {
            const char* src = (const char*)wp + (size_t)gs[s] * 32768;
            char* dst = (char*)wbuf[s];
            #pragma unroll
            for (int j = 0; j < 2; j++) {
                const int off = (j * 16 + wid) * 1024;   // wave-uniform base
                gload_lds16(src + off + lane * 16, dst + off);
            }
        }
    };

    // Trunc split A -> ah (bf16 hi) + al (bf16 of remainder); exact to ~2^-17.
    auto splitc2 = [&](f32x4 x0, f32x4 x1, bf16x8& ah, bf16x8& al) {
        u32x4 a, l;
        #pragma unroll
        for (int p = 0; p < 2; p++) {
            unsigned e0 = __float_as_uint(x0[2 * p]);
            unsigned e1 = __float_as_uint(x0[2 * p + 1]);
            a[p] = __builtin_amdgcn_perm(e1, e0, 0x07060302u);
            float d0 = x0[2 * p]     - __uint_as_float(e0 & 0xffff0000u);
            float d1 = x0[2 * p + 1] - __uint_as_float(e1 & 0xffff0000u);
            l[p] = __builtin_amdgcn_perm(__float_as_uint(d1), __float_as_uint(d0), 0x07060302u);
            unsigned f0 = __float_as_uint(x1[2 * p]);
            unsigned f1 = __float_as_uint(x1[2 * p + 1]);
            a[2 + p] = __builtin_amdgcn_perm(f1, f0, 0x07060302u);
            float g0 = x1[2 * p]     - __uint_as_float(f0 & 0xffff0000u);
            float g1 = x1[2 * p + 1] - __uint_as_float(f1 & 0xffff0000u);
            l[2 + p] = __builtin_amdgcn_perm(__float_as_uint(g1), __float_as_uint(g0), 0x07060302u);
        }
        ah = *(const bf16x8*)&a;
        al = *(const bf16x8*)&l;
    };

    // acc[0..3] = A @ W[slot][:, hb4*16 .. +64] (2-term), zero-inits acc
    auto gemmHalf = [&](int slot, const float* pA, int hb4, f32x4* acc) {
        #pragma unroll
        for (int f = 0; f < 4; f++) acc[f] = (f32x4){0.f, 0.f, 0.f, 0.f};
        const unsigned short* wb = wbuf[slot];
        #pragma unroll
        for (int c = 0; c < 4; c++) {
            const float* p = pA + c * 32 + agrp * 8;
            bf16x8 ah, al;
            splitc2(*(const f32x4*)p, *(const f32x4*)(p + 4), ah, al);
            __builtin_amdgcn_s_setprio(1);
            #pragma unroll
            for (int fl = 0; fl < 4; fl++) {
                const bf16x8 w = *(const bf16x8*)(&wb[(size_t)(c * 8 + hb4 + fl) * 512 + lane * 8]);
                acc[fl] = __builtin_amdgcn_mfma_f32_16x16x32_bf16(ah, w, acc[fl], 0, 0, 0);
                acc[fl] = __builtin_amdgcn_mfma_f32_16x16x32_bf16(al, w, acc[fl], 0, 0, 0);
            }
            __builtin_amdgcn_s_setprio(0);
        }
    };

    // acc8 += A @ W[slot] (full 128 cols, 2-term)
    auto gemmFull = [&](int slot, const float* pA, f32x4* acc8) {
        const unsigned short* wb = wbuf[slot];
        #pragma unroll
        for (int c = 0; c < 4; c++) {
            const float* p = pA + c * 32 + agrp * 8;
            bf16x8 ah, al;
            splitc2(*(const f32x4*)p, *(const f32x4*)(p + 4), ah, al);
            __builtin_amdgcn_s_setprio(1);
            #pragma unroll
            for (int f = 0; f < 8; f++) {
                const bf16x8 w = *(const bf16x8*)(&wb[(size_t)(c * 8 + f) * 512 + lane * 8]);
                acc8[f] = __builtin_amdgcn_mfma_f32_16x16x32_bf16(ah, w, acc8[f], 0, 0, 0);
                acc8[f] = __builtin_amdgcn_mfma_f32_16x16x32_bf16(al, w, acc8[f], 0, 0, 0);
            }
            __builtin_amdgcn_s_setprio(0);
        }
    };

    auto sigm = [](float x) { return 1.f / (1.f + __expf(-x)); };
    auto tanh_ = [](float x) {
        x = fminf(18.f, fmaxf(-18.f, x));
        float e = __expf(2.f * x);
        return (e - 1.f) / (e + 1.f);
    };

    // ================= G1: r gate =================
    stage3(6, 0, 3);                   // hr, ir, sr
    __syncthreads();
    unsigned rhp[32];                  // rh packed (hi|lo bf16), C-layout
    #pragma unroll
    for (int half = 0; half < 2; half++) {
        f32x4 hx[4], s1[4], G[4];
        gemmHalf(0, pAhid, half * 4, hx);
        gemmHalf(1, pAin,  half * 4, G);
        #pragma unroll
        for (int fl = 0; fl < 4; fl++) {
            const int col = half * 64 + fl * 16 + a16;
            const float bh = biasf[6 * 128 + col];
            const float bi = biasf[0 * 128 + col];
            #pragma unroll
            for (int j = 0; j < 4; j++) {
                hx[fl][j] += bh;
                s1[fl][j] = sigm(G[fl][j] + bi + hx[fl][j]);
            }
        }
        gemmHalf(2, pAseq, half * 4, G);
        #pragma unroll
        for (int fl = 0; fl < 4; fl++) {
            const int col = half * 64 + fl * 16 + a16;
            const float bs = biasf[3 * 128 + col];
            #pragma unroll
            for (int j = 0; j < 4; j++) {
                const int rowC = agrp * 4 + j;
                float rr = 0.5f * (s1[fl][j] + sigm(G[fl][j] + bs + hx[fl][j]));
                float h  = hid[(row0 + rowC) * 128 + col];
                float rh = rr * h;
                unsigned u = __float_as_uint(rh);
                float rem = rh - __uint_as_float(u & 0xffff0000u);
                rhp[half * 16 + fl * 4 + j] = (u & 0xffff0000u) | (__float_as_uint(rem) >> 16);
            }
        }
    }

    // ============ wave-local rh transpose (C-layout -> A-layout) ============
    __syncthreads();                   // all waves done reading G1 weights
    unsigned* slice = (wid < 12) ? ((unsigned*)wbuf) + wid * 2048
                                 : ((unsigned*)tscr) + (wid - 12) * 2048;
    #pragma unroll
    for (int half = 0; half < 2; half++)
        #pragma unroll
        for (int fl = 0; fl < 4; fl++)
            #pragma unroll
            for (int j = 0; j < 4; j++) {
                const int rowC = agrp * 4 + j;
                const int col  = half * 64 + fl * 16 + a16;
                const int swb  = ((rowC & 7) << 3) | ((rowC & 8) >> 1);
                slice[rowC * 128 + (col ^ swb)] = rhp[half * 16 + fl * 4 + j];
            }
    u32x4 rha[8];                      // A-layout: rha[c*2+t][e] = rh at k
    {
        const int swb = ((a16 & 7) << 3) | ((a16 & 8) >> 1);
        #pragma unroll
        for (int c = 0; c < 4; c++) {
            const int k0 = c * 32 + agrp * 8;
            rha[c * 2]     = *(const u32x4*)&slice[a16 * 128 + (k0 ^ swb)];
            rha[c * 2 + 1] = *(const u32x4*)&slice[a16 * 128 + ((k0 + 4) ^ swb)];
        }
    }
    __syncthreads();                   // bounce reads done; wbuf reusable

    // ================= G2: n accumulator =================
    stage3(8, 2, 5);                   // hn, in, sn
    __syncthreads();
    f32x4 nacc[8];
    #pragma unroll
    for (int f = 0; f < 8; f++) nacc[f] = (f32x4){0.f, 0.f, 0.f, 0.f};
    {   // hn: A = rh from rha (already bf16 hi/lo packed — no split VALU)
        const unsigned short* wb = wbuf[0];
        #pragma unroll
        for (int c = 0; c < 4; c++) {
            const u32x4 lo = rha[c * 2], hi = rha[c * 2 + 1];
            u32x4 av, lv;
            av[0] = __builtin_amdgcn_perm(lo[1], lo[0], 0x07060302u);
            av[1] = __builtin_amdgcn_perm(lo[3], lo[2], 0x07060302u);
            av[2] = __builtin_amdgcn_perm(hi[1], hi[0], 0x07060302u);
            av[3] = __builtin_amdgcn_perm(hi[3], hi[2], 0x07060302u);
            lv[0] = __builtin_amdgcn_perm(lo[1], lo[0], 0x05040100u);
            lv[1] = __builtin_amdgcn_perm(lo[3], lo[2], 0x05040100u);
            lv[2] = __builtin_amdgcn_perm(hi[1], hi[0], 0x05040100u);
            lv[3] = __builtin_amdgcn_perm(hi[3], hi[2], 0x05040100u);
            const bf16x8 ah = *(const bf16x8*)&av;
            const bf16x8 al = *(const bf16x8*)&lv;
            __builtin_amdgcn_s_setprio(1);
            #pragma unroll
            for (int f = 0; f < 8; f++) {
                const bf16x8 w = *(const bf16x8*)(&wb[(size_t)(c * 8 + f) * 512 + lane * 8]);
                nacc[f] = __builtin_amdgcn_mfma_f32_16x16x32_bf16(ah, w, nacc[f], 0, 0, 0);
                nacc[f] = __builtin_amdgcn_mfma_f32_16x16x32_bf16(al, w, nacc[f], 0, 0, 0);
            }
            __builtin_amdgcn_s_setprio(0);
        }
    }
    gemmFull(1, pAin,  nacc);
    gemmFull(2, pAseq, nacc);
    unsigned nh[16];                   // n = tanh(nacc+biases), f16-packed
    #pragma unroll
    for (int f = 0; f < 8; f++) {
        const int col = f * 16 + a16;
        const float bs = biasf[8 * 128 + col] + biasf[2 * 128 + col] + biasf[5 * 128 + col];
        #pragma unroll
        for (int p = 0; p < 2; p++) {
            float t0 = tanh_(nacc[f][2 * p]     + bs);
            float t1 = tanh_(nacc[f][2 * p + 1] + bs);
            f16x2 pk = __builtin_amdgcn_cvt_pkrtz(t0, t1);
            nh[f * 2 + p] = *(unsigned*)&pk;
        }
    }
    __syncthreads();                   // g2 weight readers done

    // ================= G3: z gate + blend =================
    stage3(7, 1, 4);                   // hz, iz, sz
    __syncthreads();
    #pragma unroll
    for (int half = 0; half < 2; half++) {
        f32x4 hx[4], s1[4], G[4];
        gemmHalf(0, pAhid, half * 4, hx);
        gemmHalf(1, pAin,  half * 4, G);
        #pragma unroll
        for (int fl = 0; fl < 4; fl++) {
            const int col = half * 64 + fl * 16 + a16;
            const float bh = biasf[7 * 128 + col];
            const float bi = biasf[1 * 128 + col];
            #pragma unroll
            for (int j = 0; j < 4; j++) {
                hx[fl][j] += bh;
                s1[fl][j] = sigm(G[fl][j] + bi + hx[fl][j]);
            }
        }
        gemmHalf(2, pAseq, half * 4, G);
        float* oslice = &tscr[wid * 512];       // 16x32 quarter, swizzled
        #pragma unroll
        for (int q = 0; q < 2; q++) {
            #pragma unroll
            for (int flq = 0; flq < 2; flq++) {
                const int fl = q * 2 + flq;
                const int col = half * 64 + fl * 16 + a16;
                const float bz = biasf[4 * 128 + col];
                #pragma unroll
                for (int j = 0; j < 4; j++) {
                    const int rowC = agrp * 4 + j;
                    float z = 0.5f * (s1[fl][j] + sigm(G[fl][j] + bz + hx[fl][j]));
                    float h = hid[(row0 + rowC) * 128 + col];
                    unsigned nv = nh[(half * 4 + fl) * 2 + (j >> 1)];
                    unsigned short us = (j & 1) ? (unsigned short)(nv >> 16)
                                                : (unsigned short)(nv & 0xffffu);
                    __fp16 hf; __builtin_memcpy(&hf, &us, 2);
                    float n = (float)hf;
                    float o = n + z * (h - n);
                    const int cq = flq * 16 + a16;
                    oslice[rowC * 32 + (cq ^ ((rowC & 7) << 2))] = o;
                }
            }
            const int r16 = lane >> 2;
            const int c8  = (lane & 3) * 8;
            const int sw  = (r16 & 7) << 2;
            f32x4 v0 = *(const f32x4*)&oslice[r16 * 32 + (c8 ^ sw)];
            f32x4 v1 = *(const f32x4*)&oslice[r16 * 32 + ((c8 + 4) ^ sw)];
            float* po = outp + (row0 + r16) * 128 + half * 64 + q * 32 + c8;
            *(f32x4*)po = v0;
            *(f32x4*)(po + 4) = v1;
        }
    }
}

extern "C" void kernel_launch(void* const* d_in, const int* in_sizes, int n_in,
                              void* d_out, int out_size, void* d_ws, size_t ws_size,
                              hipStream_t stream)
{
    (void)in_sizes; (void)n_in; (void)out_size; (void)ws_size;
    const float* inp  = (const float*)d_in[0];
    const float* seqp = (const float*)d_in[1];
    const float* hid  = (const float*)d_in[2];
    const float* W[9]; const float* Bv[9];
    for (int i = 0; i < 9; i++) {
        W[i]  = (const float*)d_in[3 + 2 * i];
        Bv[i] = (const float*)d_in[4 + 2 * i];
    }
    unsigned short* wp = (unsigned short*)d_ws; // needs 294,912 + 4,608 B

    pack_weights<<<9, PACK_BDIM, 0, stream>>>(W[0], W[1], W[2], W[3], W[4],
                                              W[5], W[6], W[7], W[8],
                                              Bv[0], Bv[1], Bv[2], Bv[3], Bv[4],
                                              Bv[5], Bv[6], Bv[7], Bv[8], wp);
    gru_fused<<<512, BDIM, 0, stream>>>(inp, seqp, hid, wp, (float*)d_out);
}

// Round 20
// 280.255 us; speedup vs baseline: 1.5632x; 1.5516x over previous
//
#include <hip/hip_runtime.h>

#define BDIM 512
#define PACK_BDIM 256

typedef __attribute__((ext_vector_type(8))) short bf16x8;
typedef __attribute__((ext_vector_type(4))) float f32x4;
typedef __attribute__((ext_vector_type(4))) unsigned int u32x4;

__device__ __forceinline__ unsigned short f2b(float x) {
    unsigned u = __float_as_uint(x);
    return (unsigned short)((u + 0x7fffu + ((u >> 16) & 1u)) >> 16);
}
__device__ __forceinline__ float b2f(unsigned short b) {
    return __uint_as_float(((unsigned)b) << 16);
}

typedef __attribute__((address_space(1))) const unsigned int ga_u32;
typedef __attribute__((address_space(3))) unsigned int la_u32;
__device__ __forceinline__ void gload_lds16(const void* g, void* l) {
    __builtin_amdgcn_global_load_lds((ga_u32*)g, (la_u32*)l, 16, 0, 0);
}

// Pack 9 fp32 128x128 weights into bf16 hi/lo, SEPARATED hi/lo blocks, plus
// all 9 biases (fp32) at the end. Weight layout per gemm g (65536 B):
// s=0 hi block (32 KB), s=1 lo block (32 KB); within block chunk cf=c*8+f
// (1 KB), byte=lane*16: 8 bf16 for k=c*32+(lane>>4)*8+i, n=f*16+(lane&15).
// Bias area: floats at short-offset 294912: biasf[g*128 + col].
__global__ __launch_bounds__(PACK_BDIM) void pack_weights(
    const float* __restrict__ w0, const float* __restrict__ w1,
    const float* __restrict__ w2, const float* __restrict__ w3,
    const float* __restrict__ w4, const float* __restrict__ w5,
    const float* __restrict__ w6, const float* __restrict__ w7,
    const float* __restrict__ w8,
    const float* __restrict__ b0, const float* __restrict__ b1,
    const float* __restrict__ b2, const float* __restrict__ b3,
    const float* __restrict__ b4, const float* __restrict__ b5,
    const float* __restrict__ b6, const float* __restrict__ b7,
    const float* __restrict__ b8, unsigned short* __restrict__ wp)
{
    __shared__ float wsm[16384];
    const float* W; const float* Bp;
    switch (blockIdx.x) {
        case 0: W = w0; Bp = b0; break; case 1: W = w1; Bp = b1; break;
        case 2: W = w2; Bp = b2; break; case 3: W = w3; Bp = b3; break;
        case 4: W = w4; Bp = b4; break; case 5: W = w5; Bp = b5; break;
        case 6: W = w6; Bp = b6; break; case 7: W = w7; Bp = b7; break;
        default: W = w8; Bp = b8; break;
    }
    const int tid = threadIdx.x;
    for (int i = tid; i < 16384; i += PACK_BDIM) wsm[i] = W[i];
    float* biasf = (float*)(wp + 294912);
    if (tid < 128) biasf[blockIdx.x * 128 + tid] = Bp[tid];
    __syncthreads();
    unsigned short* dst = wp + (size_t)blockIdx.x * 32768;
    for (int item = tid; item < 4096; item += PACK_BDIM) {
        const int lane = item & 63, q = item >> 6;     // q = s*32 + c*8 + f
        const int s = q >> 5, cf = q & 31, c = cf >> 3, f = cf & 7;
        const int k0 = c * 32 + (lane >> 4) * 8;
        const int n  = f * 16 + (lane & 15);
        unsigned v2[4];
        for (int i2 = 0; i2 < 4; i2++) {
            unsigned short lohi[2];
            for (int t = 0; t < 2; t++) {
                float x = wsm[(k0 + i2 * 2 + t) * 128 + n];
                unsigned short hb = f2b(x);
                if (s) { hb = (unsigned short)(__float_as_uint(x - b2f(hb)) >> 16); }
                lohi[t] = hb;
            }
            v2[i2] = (unsigned)lohi[0] | ((unsigned)lohi[1] << 16);
        }
        u32x4 vv; vv[0] = v2[0]; vv[1] = v2[1]; vv[2] = v2[2]; vv[3] = v2[3];
        *(u32x4*)(dst + (size_t)(s * 32 + cf) * 512 + lane * 8) = vv;
    }
}

// Fused dual-input GRU cell — the R13 configuration (measured optimum of the
// 19-round structural search: 279 us). grid = B/64, 512 thr = 8 waves =
// 4 rowgrp x 2 colgrp; per wave 16 rows x 64 cols -> 4-frag sets (16 regs).
// Loop over 9 phases (runtime g kills address hoisting), 2x32KB double-
// buffered weight staging, 2 co-resident blocks/CU (waves_per_eu(4))
// overlapping each other's barrier drains. 3-term bf16 split (Ah*Wh +
// Al*Wh + Ah*Wl), trunc A-split. All measured alternatives regressed:
// fewer barriers (R16 302), 32x32 MFMA (R17 438), no staging (R14 437),
// barrier-free wave-owned rows (R19 435), clean 1-block (R12 415).
// order u: 0 hr(6), 1 ir(0), 2 sr(3), 3 hn(8,LDS-A), 4 in(2), 5 sn(5),
//          6 hz(7), 7 iz(1), 8 sz(4).
__global__ __launch_bounds__(BDIM) __attribute__((amdgpu_waves_per_eu(4)))
void gru_fused(
    const float* __restrict__ inp, const float* __restrict__ seqp,
    const float* __restrict__ hid, const unsigned short* __restrict__ wp,
    float* __restrict__ outp)
{
    __shared__ __align__(16) unsigned short wbuf[2][16384]; // 2 x 32 KiB weights
    float* tb = (float*)wbuf[1];   // rh / output transpose overlay on buf1

    const int tid    = threadIdx.x;
    const int lane   = tid & 63;
    const int wid    = tid >> 6;       // 0..7
    const int rowgrp = wid >> 1;       // 0..3
    const int colgrp = wid & 1;        // 0..1
    const int agrp   = lane >> 4;      // 0..3
    const int a16    = lane & 15;
    const int ncol0  = colgrp * 64;
    const size_t row0 = (size_t)blockIdx.x * 64;
    const int locrow_a = rowgrp * 16 + a16;              // 0..63
    const int rswA = (locrow_a & 7) << 3;

    const float* pAin  = inp  + (row0 + locrow_a) * 128;
    const float* pAseq = seqp + (row0 + locrow_a) * 128;
    const float* pAhid = hid  + (row0 + locrow_a) * 128;
    const float* biasf = (const float*)(wp + 294912);

    f32x4 hx[4], s1[4], nacc[4], G[4];
    bf16x8 ahs[4];
    const f32x4 zv = {0.f, 0.f, 0.f, 0.f};

    auto stageu = [&](int g, int s, int b) {   // issue 32KB sub-stage, no wait
        const char* src = (const char*)wp + (size_t)g * 65536 + (size_t)s * 32768;
        char* dstb = (char*)wbuf[b];
        #pragma unroll
        for (int j = 0; j < 4; j++) {
            const int off = (j * 8 + wid) * 1024;  // wave-uniform LDS base
            gload_lds16(src + off + lane * 16, dstb + off);
        }
    };

    auto splitc = [&](int c, f32x4 x0, f32x4 x1) -> bf16x8 {
        bf16x8 al;
        #pragma unroll
        for (int i = 0; i < 4; i++) {
            unsigned u0 = __float_as_uint(x0[i]);
            ahs[c][i] = (short)(u0 >> 16);
            al[i] = (short)(__float_as_uint(x0[i] - __uint_as_float(u0 & 0xffff0000u)) >> 16);
            unsigned u1 = __float_as_uint(x1[i]);
            ahs[c][4 + i] = (short)(u1 >> 16);
            al[4 + i] = (short)(__float_as_uint(x1[i] - __uint_as_float(u1 & 0xffff0000u)) >> 16);
        }
        return al;
    };

    // G = Ah*Wh + Al*Wh (A from global, W from buf0); re-inits G
    auto hiU = [&](const float* pA) {
        #pragma unroll
        for (int f = 0; f < 4; f++) G[f] = zv;
        const unsigned short* wb = wbuf[0];
        #pragma unroll
        for (int c = 0; c < 4; c++) {
            const float* p = pA + c * 32 + agrp * 8;
            bf16x8 al = splitc(c, *(const f32x4*)(p), *(const f32x4*)(p + 4));
            #pragma unroll
            for (int f = 0; f < 4; f++) {
                const int fglob = colgrp * 4 + f;
                const bf16x8 wh = *(const bf16x8*)(&wb[(size_t)(c * 8 + fglob) * 512 + lane * 8]);
                G[f] = __builtin_amdgcn_mfma_f32_16x16x32_bf16(ahs[c], wh, G[f], 0, 0, 0);
                G[f] = __builtin_amdgcn_mfma_f32_16x16x32_bf16(al, wh, G[f], 0, 0, 0);
            }
        }
    };

    // G = Ah*Wh + Al*Wh with A rows from tb (XOR-swizzled)
    auto hiU_lds = [&]() {
        #pragma unroll
        for (int f = 0; f < 4; f++) G[f] = zv;
        const unsigned short* wb = wbuf[0];
        #pragma unroll
        for (int c = 0; c < 4; c++) {
            const int rk = (c * 32 + agrp * 8) ^ rswA;
            f32x4 x0 = *(const f32x4*)(&tb[locrow_a * 128 + rk]);
            f32x4 x1 = *(const f32x4*)(&tb[locrow_a * 128 + rk + 4]);
            bf16x8 al = splitc(c, x0, x1);
            #pragma unroll
            for (int f = 0; f < 4; f++) {
                const int fglob = colgrp * 4 + f;
                const bf16x8 wh = *(const bf16x8*)(&wb[(size_t)(c * 8 + fglob) * 512 + lane * 8]);
                G[f] = __builtin_amdgcn_mfma_f32_16x16x32_bf16(ahs[c], wh, G[f], 0, 0, 0);
                G[f] = __builtin_amdgcn_mfma_f32_16x16x32_bf16(al, wh, G[f], 0, 0, 0);
            }
        }
    };

    // G += Ah*Wl (W from buf1) + bias(g)
    auto loU = [&](int g) {
        const unsigned short* wb = wbuf[1];
        #pragma unroll
        for (int c = 0; c < 4; c++)
            #pragma unroll
            for (int f = 0; f < 4; f++) {
                const int fglob = colgrp * 4 + f;
                const bf16x8 wl = *(const bf16x8*)(&wb[(size_t)(c * 8 + fglob) * 512 + lane * 8]);
                G[f] = __builtin_amdgcn_mfma_f32_16x16x32_bf16(ahs[c], wl, G[f], 0, 0, 0);
            }
        #pragma unroll
        for (int f = 0; f < 4; f++) {
            float bv = biasf[g * 128 + ncol0 + f * 16 + a16];
            #pragma unroll
            for (int j = 0; j < 4; j++) G[f][j] += bv;
        }
    };

    auto sigm = [](float x) { return 1.f / (1.f + __expf(-x)); };
    auto tanh_ = [](float x) {
        x = fminf(18.f, fmaxf(-18.f, x));
        float e = __expf(2.f * x);
        return (e - 1.f) / (e + 1.f);
    };

    const unsigned long long GT = 0x417528306ULL;  // nibble u -> gemm id
    stageu(6, 0, 0);                               // prologue: hr-Wh -> buf0

    #pragma clang loop unroll(disable)
    for (int u = 0; u < 9; ++u) {
        const int g = (int)((GT >> (4 * u)) & 15);
        if (u == 3) {
            __syncthreads();           // publishes tb(rh); hn-Wh drained into buf0
            hiU_lds();                 // reads tb (buf1) + buf0
            __syncthreads();           // all tb reads done
            stageu(g, 1, 1);           // hn-Wl -> buf1 (overwrites tb)
        } else {
            __syncthreads();           // buf1 readers done; Wh(g) drained in buf0
            stageu(g, 1, 1);           // Wl(g) -> buf1
            const float* pA = (u == 0 || u == 6) ? pAhid
                            : (u == 1 || u == 4 || u == 7) ? pAin : pAseq;
            hiU(pA);
        }
        __syncthreads();               // Wl(g) drained; buf0 readers done
        if (u < 8) stageu((int)((GT >> (4 * (u + 1))) & 15), 0, 0); // Wh(next)
        loU(g);
        // ---- merge G into persistent state ----
        switch (u) {
            case 0: case 6:
                #pragma unroll
                for (int f = 0; f < 4; f++) hx[f] = G[f];
                break;
            case 1: case 7:
                #pragma unroll
                for (int f = 0; f < 4; f++)
                    #pragma unroll
                    for (int j = 0; j < 4; j++)
                        s1[f][j] = sigm(G[f][j] + hx[f][j]);
                break;
            case 2: {                  // r = 0.5(s1 + sigm(G+hx)); rh -> tb
                __syncthreads();       // all waves done with loU(buf1)
                #pragma unroll
                for (int f = 0; f < 4; f++)
                    #pragma unroll
                    for (int j = 0; j < 4; j++) {
                        int row = rowgrp * 16 + agrp * 4 + j;
                        int col = ncol0 + f * 16 + a16;
                        float r = 0.5f * (s1[f][j] + sigm(G[f][j] + hx[f][j]));
                        float h = hid[(row0 + row) * 128 + col];
                        tb[row * 128 + (col ^ ((row & 7) << 3))] = r * h;
                    }
                break;
            }
            case 3:
                #pragma unroll
                for (int f = 0; f < 4; f++) nacc[f] = G[f];
                break;
            case 4: case 5:
                #pragma unroll
                for (int f = 0; f < 4; f++) nacc[f] += G[f];
                break;
            default:                   // u == 8: G holds sz result
                break;
        }
    }

    // ---- blend: z = 0.5(s1 + sigm(G+hx)); out = (1-z)tanh(nacc) + z*h ----
    __syncthreads();                   // last loU done; buf1/tb free
    #pragma unroll
    for (int f = 0; f < 4; f++)
        #pragma unroll
        for (int j = 0; j < 4; j++) {
            int row = rowgrp * 16 + agrp * 4 + j;
            int col = ncol0 + f * 16 + a16;
            float zz = 0.5f * (s1[f][j] + sigm(G[f][j] + hx[f][j]));
            float h  = hid[(row0 + row) * 128 + col];
            float nn = tanh_(nacc[f][j]);
            tb[row * 128 + (col ^ ((row & 7) << 3))] = (1.f - zz) * nn + zz * h;
        }
    __syncthreads();
    #pragma unroll
    for (int p = 0; p < 4; p++) {
        int e = p * 2048 + tid * 4;
        int rrow = e >> 7, c0 = e & 127;
        f32x4 v = *(const f32x4*)(&tb[rrow * 128 + (c0 ^ ((rrow & 7) << 3))]);
        *(f32x4*)(&outp[(row0 + rrow) * 128 + c0]) = v;
    }
}

extern "C" void kernel_launch(void* const* d_in, const int* in_sizes, int n_in,
                              void* d_out, int out_size, void* d_ws, size_t ws_size,
                              hipStream_t stream)
{
    (void)in_sizes; (void)n_in; (void)out_size; (void)ws_size;
    const float* inp  = (const float*)d_in[0];
    const float* seqp = (const float*)d_in[1];
    const float* hid  = (const float*)d_in[2];
    const float* W[9]; const float* Bv[9];
    for (int i = 0; i < 9; i++) {
        W[i]  = (const float*)d_in[3 + 2 * i];
        Bv[i] = (const float*)d_in[4 + 2 * i];
    }
    unsigned short* wp = (unsigned short*)d_ws; // needs 589,824 + 4,608 B

    pack_weights<<<9, PACK_BDIM, 0, stream>>>(W[0], W[1], W[2], W[3], W[4],
                                              W[5], W[6], W[7], W[8],
                                              Bv[0], Bv[1], Bv[2], Bv[3], Bv[4],
                                              Bv[5], Bv[6], Bv[7], Bv[8], wp);
    gru_fused<<<2048, BDIM, 0, stream>>>(inp, seqp, hid, wp, (float*)d_out);
}